// Round 7
// baseline (9643.086 us; speedup 1.0000x reference)
//
#include <hip/hip_runtime.h>
#include <hip/hip_bf16.h>
#include <math.h>

#define BB 256     // batch
#define TT 128     // timesteps
#define NBR 16     // batch rows per group
#define BLK 512    // threads per block (8 waves)

typedef short bf8 __attribute__((ext_vector_type(8)));   // 8 bf16 (4 VGPRs)
typedef float f4  __attribute__((ext_vector_type(4)));   // MFMA accumulator
typedef unsigned long long u64;
#define MFMA16 __builtin_amdgcn_mfma_f32_16x16x32_bf16

// ---- workspace layout (bf16/short element offsets) ----
constexpr size_t U_WC0  = 0;                                   // (2,768,384)  gate-only cat l0
constexpr size_t U_WC1  = U_WC0  + (size_t)2*768*384;          // (2,768,768)  gate-only cat l1
constexpr size_t U_WCB0 = U_WC1  + (size_t)2*768*768;          // (2,1024,384) Wcomb l0
constexpr size_t U_WCB1 = U_WCB0 + (size_t)2*1024*384;         // (2,1024,768) Wcomb l1
constexpr size_t U_XP   = U_WCB1 + (size_t)2*1024*768;         // (48,512)
constexpr size_t U_OUTP = U_XP   + (size_t)48*512;             // (256,512)
constexpr size_t U_L0   = U_OUTP + (size_t)256*512;            // (B,T,512) l0 out bf16
constexpr size_t U_END  = U_L0   + (size_t)BB*TT*512;
constexpr size_t FOFF   = U_END * 2;                           // byte offset of f32 region
// f32 region (float offsets):
constexpr size_t F_BSUM0 = 0;                 // (2,1024)
constexpr size_t F_BSUM1 = F_BSUM0 + 2048;    // (2,1024)
constexpr size_t F_H0    = F_BSUM1 + 2048;    // (2,B,256)
constexpr size_t F_C0    = F_H0 + 2*BB*256;
constexpr size_t F_H1    = F_C0 + 2*BB*256;
constexpr size_t F_C1    = F_H1 + 2*BB*256;
constexpr size_t F_CNT   = F_C1 + 2*BB*256;   // 64 counters x 64-word pad (256B each)
constexpr size_t F_COMM  = F_CNT + 4096;
// per-group comm block, u64 words, ROW-MAJOR: one u64 = 4 consecutive channels of one row
constexpr int X_XM  = 0;        // 16 rows x 128 chan-quads = 2048 u64
constexpr int X_ZS  = 2048;     // 2048 u64
constexpr int X_H   = 4096;     // 16 rows x 64 quads = 1024 u64
constexpr int GSTR  = 5120;     // 40KB/group; x32 = 1.25MB

__device__ __forceinline__ short f2bs(float v) {
    __hip_bfloat16 b = __float2bfloat16(v);
    short s; __builtin_memcpy(&s, &b, 2); return s;
}
__device__ __forceinline__ float bs2f(short s) {
    unsigned int u = ((unsigned int)(unsigned short)s) << 16;
    float f; __builtin_memcpy(&f, &u, 4); return f;
}
__device__ __forceinline__ float sigmoidf_(float x) { return 1.0f / (1.0f + __expf(-x)); }
__device__ __forceinline__ float tanhf_(float x) {
    float e = __expf(-2.0f * fabsf(x));
    float t = (1.0f - e) / (1.0f + e);
    return copysignf(t, x);
}
// cheap softplus: log1p(y)->__logf(1+y) for y in (0,1]; abs err <1e-7 where it matters
__device__ __forceinline__ float softplusf_(float x) {
    return __logf(1.0f + __expf(-fabsf(x))) + fmaxf(x, 0.0f);
}
__device__ __forceinline__ short conv2bs(float v) { return f2bs(v); }
__device__ __forceinline__ short conv2bs(short v) { return v; }
__device__ __forceinline__ void storeval(float* p, float v) { *p = v; }
__device__ __forceinline__ void storeval(short* p, float v) { *p = f2bs(v); }
__device__ __forceinline__ short sel4(u64 v, int s) { return (short)(v >> (16*s)); }

// device-scope (cross-XCD coherent) comm accessors, 8-byte
__device__ __forceinline__ void a_stU(u64* p, u64 v) {
    __hip_atomic_store(p, v, __ATOMIC_RELAXED, __HIP_MEMORY_SCOPE_AGENT);
}
__device__ __forceinline__ u64 a_ldU(u64* p) {
    return __hip_atomic_load(p, __ATOMIC_RELAXED, __HIP_MEMORY_SCOPE_AGENT);
}
// split flag-sync (r6-proven protocol, relaxed add; __syncthreads drains vmcnt first)
__device__ __forceinline__ void gsync_arrive(unsigned* cnt) {
    __syncthreads();
    if (threadIdx.x == 0)
        __hip_atomic_fetch_add(cnt, 1u, __ATOMIC_RELAXED, __HIP_MEMORY_SCOPE_AGENT);
}
__device__ __forceinline__ void gsync_wait(unsigned* cnt, unsigned target) {
    if (threadIdx.x == 0)
        while (__hip_atomic_load(cnt, __ATOMIC_RELAXED, __HIP_MEMORY_SCOPE_AGENT) < target)
            __builtin_amdgcn_s_sleep(1);
    __syncthreads();
    asm volatile("" ::: "memory");
}

// ---------------- prep: gate-only cat, xp/outp bf16, bsum, zero states+counters ----
__global__ __launch_bounds__(256)
void prep2(const float* __restrict__ w_ih_l0, const float* __restrict__ w_hh_l0,
           const float* __restrict__ b_ih_l0, const float* __restrict__ b_hh_l0,
           const float* __restrict__ w_ih_l1, const float* __restrict__ w_hh_l1,
           const float* __restrict__ b_ih_l1, const float* __restrict__ b_hh_l1,
           const float* __restrict__ x_proj_w, const float* __restrict__ out_proj_w,
           short* __restrict__ wsu, float* __restrict__ wsf)
{
    const int nt = gridDim.x * blockDim.x;
    const int g0 = blockIdx.x * blockDim.x + threadIdx.x;

    for (int idx = g0; idx < 2*768*384; idx += nt) {
        int dir = idx / (768*384), rem = idx % (768*384);
        int n = rem / 384, k = rem % 384, row = 256 + n;
        float v = (k < 128) ? w_ih_l0[(size_t)dir*1024*128 + (size_t)row*128 + k]
                            : w_hh_l0[(size_t)dir*1024*256 + (size_t)row*256 + (k-128)];
        wsu[U_WC0 + idx] = f2bs(v);
    }
    for (int idx = g0; idx < 2*768*768; idx += nt) {
        int dir = idx / (768*768), rem = idx % (768*768);
        int n = rem / 768, k = rem % 768, row = 256 + n;
        float v = (k < 512) ? w_ih_l1[(size_t)dir*1024*512 + (size_t)row*512 + k]
                            : w_hh_l1[(size_t)dir*1024*256 + (size_t)row*256 + (k-512)];
        wsu[U_WC1 + idx] = f2bs(v);
    }
    for (int idx = g0; idx < 48*512;  idx += nt) wsu[U_XP   + idx] = f2bs(x_proj_w[idx]);
    for (int idx = g0; idx < 256*512; idx += nt) wsu[U_OUTP + idx] = f2bs(out_proj_w[idx]);
    for (int idx = g0; idx < 2048; idx += nt) {
        wsf[F_BSUM0 + idx] = b_ih_l0[idx] + b_hh_l0[idx];
        wsf[F_BSUM1 + idx] = b_ih_l1[idx] + b_hh_l1[idx];
    }
    for (int idx = g0; idx < 2*BB*256; idx += nt) {
        wsf[F_H0 + idx] = 0.0f;
        wsf[F_C0 + idx] = 0.0f;
    }
    unsigned* cnt = (unsigned*)(wsf + F_CNT);
    for (int idx = g0; idx < 4096; idx += nt) cnt[idx] = 0;
}

// ---------------- Wcomb = in_proj_w(1024x256) @ Wcat_um(2,256,KG), f32, ->bf16 ----
template<int DIN>
__global__ __launch_bounds__(256)
void wcomb_gemm(const float* __restrict__ inp,   // (1024,256)
                const float* __restrict__ wih,   // (2,1024,DIN)
                const float* __restrict__ whh,   // (2,1024,256)
                short* __restrict__ outw)        // (2,1024,KG)
{
    constexpr int KG = DIN + 256;
    __shared__ float As[16][17], Bs[16][17];
    const int tx = threadIdx.x & 15, ty = threadIdx.x >> 4;
    const int n = blockIdx.x*16 + ty;
    const int k = blockIdx.y*16 + tx;
    const int dir = blockIdx.z;
    float acc = 0.f;
    for (int m0 = 0; m0 < 256; m0 += 16) {
        As[ty][tx] = inp[(size_t)n*256 + m0 + tx];
        int m = m0 + ty;
        Bs[ty][tx] = (k < DIN) ? wih[((size_t)dir*1024 + m)*DIN + k]
                               : whh[((size_t)dir*1024 + m)*256 + (k - DIN)];
        __syncthreads();
        #pragma unroll
        for (int mm = 0; mm < 16; ++mm) acc = fmaf(As[ty][mm], Bs[mm][tx], acc);
        __syncthreads();
    }
    outw[((size_t)dir*1024 + n)*KG + k] = f2bs(acc);
}

// ---------------- cooperative layer kernel: 32 groups x 8 members ----------------
// S_a (xm/zs) exposed; S_b (h) hidden behind next-step's u-part GEMM (G1a).
template<int DIN, typename TIn, typename TOut>
__global__ __launch_bounds__(BLK)
void layer_coop(const TIn* __restrict__ in,        // (B,T,DIN)
                TOut* __restrict__ out,             // (B,T,512): dir writes [dir*256,+256)
                const short* __restrict__ Wg_,      // (2,768,KG) gate-only bf16
                const short* __restrict__ Wcb_,     // (2,1024,KG) Wcomb bf16
                const short* __restrict__ Wxp,      // (48,512)
                const short* __restrict__ Woutp,    // (256,512)
                const float* __restrict__ bsum_all, // (2,1024)
                const float* __restrict__ conv_w,   // (512,2)
                const float* __restrict__ conv_b,   // (512)
                const float* __restrict__ dtw,      // (512,16)
                const float* __restrict__ dtb,      // (512)
                const float* __restrict__ Dm,       // (512)
                const float* __restrict__ h_init, const float* __restrict__ c_init,
                float* __restrict__ h_fin, float* __restrict__ c_fin,
                u64* commAll, unsigned* cntAll, int layer)
{
    constexpr int KG = DIN + 256;
    constexpr int ASTR = DIN + 264;       // sA row stride (shorts)
    constexpr int NU = 16*DIN/BLK;        // u elems per thread
    const int tid = threadIdx.x;
    const int wv = tid >> 6, ln = tid & 63;
    const int lr = ln & 15, lq = ln >> 4;
    const int bid = blockIdx.x;
    const int xcd = bid & 7, slot = bid >> 3;
    const int g = xcd * 4 + (slot >> 3);           // group 0..31 (same-XCD packing heuristic)
    const int j = slot & 7;                        // member 0..7
    const int dir = g >> 4;
    const int b0 = (g & 15) * NBR;

    u64* cu = commAll + (size_t)g * GSTR;
    unsigned* cnt = cntAll + (layer * 32 + g) * 64;

    const short* Wg  = Wg_  + (size_t)dir * 768  * KG;
    const short* Wcb = Wcb_ + (size_t)dir * 1024 * KG;

    __shared__ __attribute__((aligned(16))) short sA[16*ASTR];   // [u | h]
    __shared__ __attribute__((aligned(16))) short sXm[16*520];   // full xm, y in-place
    __shared__ __attribute__((aligned(16))) short sZs[16*520];   // full silu(z)
    __shared__ __attribute__((aligned(16))) short sWxp[48*520];  // Wxp cached
    __shared__ __attribute__((aligned(16))) short sWo[32*520];   // Woutp own 32 rows cached
    __shared__ __attribute__((aligned(16))) short sT[8*256];     // per-wave 16x16 transpose tile
    __shared__ float sFs[16*36], sGs[16*36], sOs[16*36], sC[16*36];
    __shared__ float sXd[16*52];
    __shared__ float sBc[16];

    // ---- init ----
    for (int idx = tid; idx < 16*256; idx += BLK) {
        int r = idx >> 8, k = idx & 255;
        sA[r*ASTR + DIN + k] = f2bs(h_init[((size_t)dir*BB + b0 + r)*256 + k]);
    }
    for (int idx = tid; idx < 16*32; idx += BLK) {
        int r = idx >> 5, kk = idx & 31;
        sC[r*36 + kk] = c_init[((size_t)dir*BB + b0 + r)*256 + 32*j + kk];
    }
    for (int idx = tid; idx < 48*512; idx += BLK) {
        int r = idx >> 9, k = idx & 511;
        sWxp[r*520 + k] = Wxp[idx];
    }
    for (int idx = tid; idx < 32*512; idx += BLK) {
        int r = idx >> 9, k = idx & 511;
        sWo[r*520 + k] = Woutp[(size_t)(32*j + r)*512 + k];
    }
    // per-lane constants
    const int q1 = wv >> 1, sub = wv & 1;
    const int kk1 = 16*sub + lr;                   // local col in own 32-strip (G1, wv<6)
    const int n1 = 256*q1 + 32*j + kk1;            // gate-only Wcat' row
    const float bs1 = (wv < 6) ? bsum_all[dir*1024 + 256 + n1] : 0.f;
    const int ncl = 16*wv + lr;                    // fused-G2 local col 0..127
    const int c1 = 128*j + ncl;                    // xz channel
    float cw = 0.f, cb = 0.f;
    if (j < 4) { cw = conv_w[c1*2 + 1]; cb = conv_b[c1]; }
    const int nloc = wv*16 + lr;                   // G4 local col (valid wv<2)
    const int col4 = 32*j + nloc;
    const float bs4 = (wv < 2) ? bsum_all[dir*1024 + col4] : 0.f;
    float w16[16];
    #pragma unroll
    for (int p = 0; p < 16; ++p) w16[p] = dtw[tid*16 + p];
    const float dtbv = dtb[tid], Dmv = Dm[tid];

    // prefetch u(0) and stage it into sA
    TIn utmp[NU];
    {
        const int tn = dir ? (TT-1) : 0;
        #pragma unroll
        for (int qq = 0; qq < NU; ++qq) {
            int idx = tid + qq*BLK;
            utmp[qq] = in[((size_t)(b0 + idx/DIN)*TT + tn)*DIN + (idx % DIN)];
        }
        #pragma unroll
        for (int qq = 0; qq < NU; ++qq) {
            int idx = tid + qq*BLK;
            sA[(idx/DIN)*ASTR + (idx % DIN)] = conv2bs(utmp[qq]);
        }
    }
    __syncthreads();

    // ---- software-pipelined fused GEMM: carried accumulators + u-part (G1a) ----
    f4 accG, accC;
    const int arow = lr*ASTR + lq*8;
    const short* browG = &Wg[(size_t)(wv < 6 ? n1 : 0)*KG + lq*8];
    const short* browC = &Wcb[(size_t)c1*KG + lq*8];

    auto g1a = [&]() {
        accG = (f4){0.f,0.f,0.f,0.f};
        accC = (f4){0.f,0.f,0.f,0.f};
        #pragma unroll 4
        for (int k0 = 0; k0 < DIN; k0 += 32) {
            bf8 a = *(const bf8*)&sA[arow + k0];
            if (wv < 6) { bf8 b = *(const bf8*)&browG[k0]; accG = MFMA16(a, b, accG, 0, 0, 0); }
            bf8 b2 = *(const bf8*)&browC[k0]; accC = MFMA16(a, b2, accC, 0, 0, 0);
        }
    };
    g1a();   // prologue: u(0)-part

    unsigned target = 8;

    for (int t = 0; t < TT; ++t) {
        const int t_in = dir ? (TT-1-t) : t;

        // ---- S_b wait (t>0) + stage h (contiguous b64 writes) ----
        if (t > 0) {
            gsync_wait(cnt, target); target += 8;
            for (int idx = tid; idx < 1024; idx += BLK)
                *(u64*)&sA[(idx>>6)*ASTR + DIN + 4*(idx & 63)] = a_ldU(&cu[X_H + idx]);
            __syncthreads();
        }

        // ---- G1b: h-part accumulation (k = DIN..KG) ----
        #pragma unroll 4
        for (int k0 = DIN; k0 < KG; k0 += 32) {
            bf8 a = *(const bf8*)&sA[arow + k0];
            if (wv < 6) { bf8 b = *(const bf8*)&browG[k0]; accG = MFMA16(a, b, accG, 0, 0, 0); }
            bf8 b2 = *(const bf8*)&browC[k0]; accC = MFMA16(a, b2, accC, 0, 0, 0);
        }
        // ---- epilogue: xm/zs wave-local transpose-publish + gate strips ----
        {
            short* tT = &sT[wv*256];
            #pragma unroll
            for (int jj = 0; jj < 4; ++jj) {
                float v = accC[jj];
                if (j < 4) v = fmaf(v, cw, cb);
                v = v * sigmoidf_(v);
                tT[(lq*4+jj)*16 + lr] = f2bs(v);
            }
            if (wv < 6) {
                #pragma unroll
                for (int jj = 0; jj < 4; ++jj) {
                    float v = accG[jj] + bs1;
                    int rr2 = lq*4 + jj;
                    if (q1 == 0)      sFs[rr2*36 + kk1] = sigmoidf_(v);
                    else if (q1 == 1) sGs[rr2*36 + kk1] = tanhf_(v);
                    else              sOs[rr2*36 + kk1] = sigmoidf_(v);
                }
            }
            asm volatile("s_waitcnt lgkmcnt(0)" ::: "memory");
            __builtin_amdgcn_sched_barrier(0);
            const int rr = ln >> 2, cc = ln & 3;
            u64 val = *(const u64*)&tT[rr*16 + 4*cc];
            if (j < 4) a_stU(&cu[X_XM + rr*128 + 32*j     + 4*wv + cc], val);
            else       a_stU(&cu[X_ZS + rr*128 + 32*(j-4) + 4*wv + cc], val);
        }
        gsync_arrive(cnt);                       // S_a arrive
        gsync_wait(cnt, target); target += 8;    // S_a wait

        // ---- stage xm (contiguous b64) + issue u(t+1) prefetch ----
        for (int idx = tid; idx < 2048; idx += BLK)
            *(u64*)&sXm[(idx>>7)*520 + 4*(idx & 127)] = a_ldU(&cu[X_XM + idx]);
        if (t + 1 < TT) {
            const int tn = dir ? (TT-2-t) : (t+1);
            #pragma unroll
            for (int qq = 0; qq < NU; ++qq) {
                int idx = tid + qq*BLK;
                utmp[qq] = in[((size_t)(b0 + idx/DIN)*TT + tn)*DIN + (idx % DIN)];
            }
        }
        __syncthreads();

        // ---- G3 (waves 0-2) || zs staging (waves 3-7) ----
        if (wv < 3) {
            f4 acc = (f4){0.f,0.f,0.f,0.f};
            const int arow3 = lr*520 + lq*8;
            const short* brow = &sWxp[(wv*16 + lr)*520 + lq*8];
            #pragma unroll 4
            for (int k0 = 0; k0 < 512; k0 += 32) {
                bf8 a = *(const bf8*)&sXm[arow3 + k0];
                bf8 b = *(const bf8*)&brow[k0];
                acc = MFMA16(a, b, acc, 0, 0, 0);
            }
            #pragma unroll
            for (int jj = 0; jj < 4; ++jj)
                sXd[(lq*4+jj)*52 + wv*16 + lr] = acc[jj];
        } else {
            for (int idx = tid - 192; idx < 2048; idx += BLK - 192)
                *(u64*)&sZs[(idx>>7)*520 + 4*(idx & 127)] = a_ldU(&cu[X_ZS + idx]);
        }
        __syncthreads();

        // ---- phase4a: dp per (chan=tid, all rows); bc once by 16 threads ----
        float dpv[16];
        #pragma unroll
        for (int r = 0; r < 16; ++r) {
            float dp = dtbv;
            #pragma unroll
            for (int p = 0; p < 16; ++p) dp = fmaf(sXd[r*52 + p], w16[p], dp);
            dpv[r] = dp;
        }
        if (tid < 16) {
            float bc = 0.f;
            #pragma unroll
            for (int s = 0; s < 16; ++s) bc = fmaf(sXd[tid*52+16+s], sXd[tid*52+32+s], bc);
            sBc[tid] = bc;
        }
        __syncthreads();
        // ---- phase4b: y = (softplus(dp)*bc + Dm) * xm * silu(z), in-place ----
        #pragma unroll
        for (int r = 0; r < 16; ++r) {
            float xmv = bs2f(sXm[r*520 + tid]);
            float zsv = bs2f(sZs[r*520 + tid]);
            float yv = fmaf(softplusf_(dpv[r]), sBc[r], Dmv) * xmv * zsv;
            sXm[r*520 + tid] = f2bs(yv);
        }
        __syncthreads();

        // ---- G4 (wv<2): own 32 cols; c/h update; out-write; transpose-publish h ----
        if (wv < 2) {
            f4 acc = (f4){0.f,0.f,0.f,0.f};
            const int arow4 = lr*520 + lq*8;
            const short* brow = &sWo[nloc*520 + lq*8];
            #pragma unroll 4
            for (int k0 = 0; k0 < 512; k0 += 32) {
                bf8 a = *(const bf8*)&sXm[arow4 + k0];
                bf8 b = *(const bf8*)&brow[k0];
                acc = MFMA16(a, b, acc, 0, 0, 0);
            }
            short* tT = &sT[wv*256];
            #pragma unroll
            for (int jj = 0; jj < 4; ++jj) {
                int r = lq*4 + jj;
                float i_t = sigmoidf_(acc[jj] + bs4);
                float cv = fmaf(sFs[r*36 + nloc], sC[r*36 + nloc], i_t * sGs[r*36 + nloc]);
                sC[r*36 + nloc] = cv;
                float hv = sOs[r*36 + nloc] * tanhf_(cv);
                tT[r*16 + lr] = f2bs(hv);
                storeval(&out[((size_t)(b0+r)*TT + t_in)*512 + (size_t)dir*256 + col4], hv);
            }
            asm volatile("s_waitcnt lgkmcnt(0)" ::: "memory");
            __builtin_amdgcn_sched_barrier(0);
            const int rr = ln >> 2, cc = ln & 3;
            u64 val = *(const u64*)&tT[rr*16 + 4*cc];
            a_stU(&cu[X_H + rr*64 + 8*j + 4*wv + cc], val);
        }
        gsync_arrive(cnt);   // S_b arrive (wait happens at next loop-top, hidden below)

        // ---- hide S_b: stage u(t+1), run next step's u-part GEMM ----
        if (t + 1 < TT) {
            #pragma unroll
            for (int qq = 0; qq < NU; ++qq) {
                int idx = tid + qq*BLK;
                sA[(idx/DIN)*ASTR + (idx % DIN)] = conv2bs(utmp[qq]);
            }
            __syncthreads();
            g1a();
        }
    }

    gsync_wait(cnt, target);   // final S_b
    // ---- finals: own 32-col slice (h from comm, c from LDS) ----
    for (int idx = tid; idx < 16*32; idx += BLK) {
        int r = idx >> 5, kk = idx & 31;
        int col = 32*j + kk;
        u64 v = a_ldU(&cu[X_H + r*64 + (col >> 2)]);
        size_t dst = ((size_t)dir*BB + b0 + r)*256 + col;
        h_fin[dst] = bs2f(sel4(v, col & 3));
        c_fin[dst] = sC[r*36 + kk];
    }
}

extern "C" void kernel_launch(void* const* d_in, const int* in_sizes, int n_in,
                              void* d_out, int out_size, void* d_ws, size_t ws_size,
                              hipStream_t stream)
{
    const float* x          = (const float*)d_in[0];
    const float* w_ih_l0    = (const float*)d_in[1];
    const float* w_hh_l0    = (const float*)d_in[2];
    const float* b_ih_l0    = (const float*)d_in[3];
    const float* b_hh_l0    = (const float*)d_in[4];
    const float* w_ih_l1    = (const float*)d_in[5];
    const float* w_hh_l1    = (const float*)d_in[6];
    const float* b_ih_l1    = (const float*)d_in[7];
    const float* b_hh_l1    = (const float*)d_in[8];
    const float* in_proj_w  = (const float*)d_in[9];
    const float* conv_w     = (const float*)d_in[10];
    const float* conv_b     = (const float*)d_in[11];
    const float* x_proj_w   = (const float*)d_in[12];
    const float* dt_proj_w  = (const float*)d_in[13];
    const float* dt_proj_b  = (const float*)d_in[14];
    const float* D_m        = (const float*)d_in[15];
    const float* out_proj_w = (const float*)d_in[16];

    short* wsu = (short*)d_ws;
    float* wsf = (float*)((char*)d_ws + FOFF);
    unsigned* cntAll = (unsigned*)(wsf + F_CNT);
    u64* commAll     = (u64*)(wsf + F_COMM);

    prep2<<<512, 256, 0, stream>>>(
        w_ih_l0, w_hh_l0, b_ih_l0, b_hh_l0,
        w_ih_l1, w_hh_l1, b_ih_l1, b_hh_l1,
        x_proj_w, out_proj_w, wsu, wsf);

    // Wcomb = in_proj_w @ Wcat_um (f32 accumulate, bf16 store)
    {
        dim3 g0(1024/16, 384/16, 2);
        wcomb_gemm<128><<<g0, 256, 0, stream>>>(in_proj_w, w_ih_l0, w_hh_l0, wsu + U_WCB0);
        dim3 g1(1024/16, 768/16, 2);
        wcomb_gemm<512><<<g1, 256, 0, stream>>>(in_proj_w, w_ih_l1, w_hh_l1, wsu + U_WCB1);
    }

    // layer 0: x fp32 (DIN=128) -> l0out bf16; finals -> H1/C1
    layer_coop<128, float, short><<<256, BLK, 0, stream>>>(
        x, wsu + U_L0,
        wsu + U_WC0, wsu + U_WCB0, wsu + U_XP, wsu + U_OUTP,
        wsf + F_BSUM0, conv_w, conv_b, dt_proj_w, dt_proj_b, D_m,
        wsf + F_H0, wsf + F_C0, wsf + F_H1, wsf + F_C1,
        commAll, cntAll, 0);

    // layer 1: l0out bf16 (DIN=512) -> d_out fp32; init from H1/C1
    layer_coop<512, short, float><<<256, BLK, 0, stream>>>(
        wsu + U_L0, (float*)d_out,
        wsu + U_WC1, wsu + U_WCB1, wsu + U_XP, wsu + U_OUTP,
        wsf + F_BSUM1, conv_w, conv_b, dt_proj_w, dt_proj_b, D_m,
        wsf + F_H1, wsf + F_C1, wsf + F_H0, wsf + F_C0,
        commAll, cntAll, 1);
}

// Round 9
// 4454.648 us; speedup vs baseline: 2.1647x; 2.1647x over previous
//
#include <hip/hip_runtime.h>
#include <hip/hip_bf16.h>
#include <math.h>

#define BB 256     // batch
#define TT 128     // timesteps
#define NBR 16     // batch rows per group
#define BLK 512    // threads per block (8 waves)

typedef short bf8 __attribute__((ext_vector_type(8)));   // 8 bf16 (4 VGPRs)
typedef float f4  __attribute__((ext_vector_type(4)));   // MFMA accumulator
typedef unsigned long long u64;
#define MFMA16 __builtin_amdgcn_mfma_f32_16x16x32_bf16

// ---- workspace layout (bf16/short element offsets) ----
constexpr size_t U_WC0  = 0;                                   // (2,768,384)  gate-only cat l0
constexpr size_t U_WC1  = U_WC0  + (size_t)2*768*384;          // (2,768,768)  gate-only cat l1
constexpr size_t U_WCB0 = U_WC1  + (size_t)2*768*768;          // (2,1024,384) Wcomb l0
constexpr size_t U_WCB1 = U_WCB0 + (size_t)2*1024*384;         // (2,1024,768) Wcomb l1
constexpr size_t U_XP   = U_WCB1 + (size_t)2*1024*768;         // (48,512)
constexpr size_t U_OUTP = U_XP   + (size_t)48*512;             // (256,512)
constexpr size_t U_L0   = U_OUTP + (size_t)256*512;            // (B,T,512) l0 out bf16
constexpr size_t U_END  = U_L0   + (size_t)BB*TT*512;
constexpr size_t FOFF   = U_END * 2;                           // byte offset of f32 region
// f32 region (float offsets):
constexpr size_t F_BSUM0 = 0;                 // (2,1024)
constexpr size_t F_BSUM1 = F_BSUM0 + 2048;    // (2,1024)
constexpr size_t F_H0    = F_BSUM1 + 2048;    // (2,B,256)
constexpr size_t F_C0    = F_H0 + 2*BB*256;
constexpr size_t F_H1    = F_C0 + 2*BB*256;
constexpr size_t F_C1    = F_H1 + 2*BB*256;
constexpr size_t F_CNT   = F_C1 + 2*BB*256;   // 64 counters x 64-word pad (256B each)
constexpr size_t F_COMM  = F_CNT + 4096;
// per-group comm block, u64 words, ROW-MAJOR: one u64 = 4 consecutive channels of one row
constexpr int X_XM  = 0;        // 16 rows x 128 chan-quads = 2048 u64
constexpr int X_ZS  = 2048;     // 2048 u64
constexpr int X_H   = 4096;     // 16 rows x 64 quads = 1024 u64
constexpr int GSTR  = 5120;     // 40KB/group; x32 = 1.25MB

__device__ __forceinline__ short f2bs(float v) {
    __hip_bfloat16 b = __float2bfloat16(v);
    short s; __builtin_memcpy(&s, &b, 2); return s;
}
__device__ __forceinline__ float bs2f(short s) {
    unsigned int u = ((unsigned int)(unsigned short)s) << 16;
    float f; __builtin_memcpy(&f, &u, 4); return f;
}
__device__ __forceinline__ float sigmoidf_(float x) { return 1.0f / (1.0f + __expf(-x)); }
__device__ __forceinline__ float tanhf_(float x) {
    float e = __expf(-2.0f * fabsf(x));
    float t = (1.0f - e) / (1.0f + e);
    return copysignf(t, x);
}
// cheap softplus: log1p(y)->__logf(1+y) for y in (0,1]; abs err <1e-7 at bf16 tolerance
__device__ __forceinline__ float softplusf_(float x) {
    return __logf(1.0f + __expf(-fabsf(x))) + fmaxf(x, 0.0f);
}
__device__ __forceinline__ short conv2bs(float v) { return f2bs(v); }
__device__ __forceinline__ short conv2bs(short v) { return v; }
__device__ __forceinline__ void storeval(float* p, float v) { *p = v; }
__device__ __forceinline__ void storeval(short* p, float v) { *p = f2bs(v); }
__device__ __forceinline__ short sel4(u64 v, int s) { return (short)(v >> (16*s)); }

// device-scope (cross-XCD coherent) comm accessors, 8-byte
__device__ __forceinline__ void a_stU(u64* p, u64 v) {
    __hip_atomic_store(p, v, __ATOMIC_RELAXED, __HIP_MEMORY_SCOPE_AGENT);
}
__device__ __forceinline__ u64 a_ldU(u64* p) {
    return __hip_atomic_load(p, __ATOMIC_RELAXED, __HIP_MEMORY_SCOPE_AGENT);
}
// r6-proven flag-sync: relaxed add (data stores are agent-scope; __syncthreads drains vmcnt)
__device__ __forceinline__ void gsync(unsigned* cnt, unsigned target) {
    __syncthreads();
    if (threadIdx.x == 0) {
        __hip_atomic_fetch_add(cnt, 1u, __ATOMIC_RELAXED, __HIP_MEMORY_SCOPE_AGENT);
        while (__hip_atomic_load(cnt, __ATOMIC_RELAXED, __HIP_MEMORY_SCOPE_AGENT) < target)
            __builtin_amdgcn_s_sleep(1);
    }
    __syncthreads();
    asm volatile("" ::: "memory");
}
// wave-local LDS transpose fence: the tile is written as shorts and read back as u64
// (TBAA lets the compiler reorder those without this). lgkmcnt(0) + sched_barrier is
// the r7-proven fence (removing it in r8 caused absmax 0.11).
__device__ __forceinline__ void tfence() {
    asm volatile("s_waitcnt lgkmcnt(0)" ::: "memory");
    __builtin_amdgcn_sched_barrier(0);
}

// ---------------- prep: gate-only cat, xp/outp bf16, bsum, zero states+counters ----
__global__ __launch_bounds__(256)
void prep2(const float* __restrict__ w_ih_l0, const float* __restrict__ w_hh_l0,
           const float* __restrict__ b_ih_l0, const float* __restrict__ b_hh_l0,
           const float* __restrict__ w_ih_l1, const float* __restrict__ w_hh_l1,
           const float* __restrict__ b_ih_l1, const float* __restrict__ b_hh_l1,
           const float* __restrict__ x_proj_w, const float* __restrict__ out_proj_w,
           short* __restrict__ wsu, float* __restrict__ wsf)
{
    const int nt = gridDim.x * blockDim.x;
    const int g0 = blockIdx.x * blockDim.x + threadIdx.x;

    for (int idx = g0; idx < 2*768*384; idx += nt) {
        int dir = idx / (768*384), rem = idx % (768*384);
        int n = rem / 384, k = rem % 384, row = 256 + n;
        float v = (k < 128) ? w_ih_l0[(size_t)dir*1024*128 + (size_t)row*128 + k]
                            : w_hh_l0[(size_t)dir*1024*256 + (size_t)row*256 + (k-128)];
        wsu[U_WC0 + idx] = f2bs(v);
    }
    for (int idx = g0; idx < 2*768*768; idx += nt) {
        int dir = idx / (768*768), rem = idx % (768*768);
        int n = rem / 768, k = rem % 768, row = 256 + n;
        float v = (k < 512) ? w_ih_l1[(size_t)dir*1024*512 + (size_t)row*512 + k]
                            : w_hh_l1[(size_t)dir*1024*256 + (size_t)row*256 + (k-512)];
        wsu[U_WC1 + idx] = f2bs(v);
    }
    for (int idx = g0; idx < 48*512;  idx += nt) wsu[U_XP   + idx] = f2bs(x_proj_w[idx]);
    for (int idx = g0; idx < 256*512; idx += nt) wsu[U_OUTP + idx] = f2bs(out_proj_w[idx]);
    for (int idx = g0; idx < 2048; idx += nt) {
        wsf[F_BSUM0 + idx] = b_ih_l0[idx] + b_hh_l0[idx];
        wsf[F_BSUM1 + idx] = b_ih_l1[idx] + b_hh_l1[idx];
    }
    for (int idx = g0; idx < 2*BB*256; idx += nt) {
        wsf[F_H0 + idx] = 0.0f;
        wsf[F_C0 + idx] = 0.0f;
    }
    unsigned* cnt = (unsigned*)(wsf + F_CNT);
    for (int idx = g0; idx < 4096; idx += nt) cnt[idx] = 0;
}

// ---------------- Wcomb = in_proj_w(1024x256) @ Wcat_um(2,256,KG), f32, ->bf16 ----
template<int DIN>
__global__ __launch_bounds__(256)
void wcomb_gemm(const float* __restrict__ inp,   // (1024,256)
                const float* __restrict__ wih,   // (2,1024,DIN)
                const float* __restrict__ whh,   // (2,1024,256)
                short* __restrict__ outw)        // (2,1024,KG)
{
    constexpr int KG = DIN + 256;
    __shared__ float As[16][17], Bs[16][17];
    const int tx = threadIdx.x & 15, ty = threadIdx.x >> 4;
    const int n = blockIdx.x*16 + ty;
    const int k = blockIdx.y*16 + tx;
    const int dir = blockIdx.z;
    float acc = 0.f;
    for (int m0 = 0; m0 < 256; m0 += 16) {
        As[ty][tx] = inp[(size_t)n*256 + m0 + tx];
        int m = m0 + ty;
        Bs[ty][tx] = (k < DIN) ? wih[((size_t)dir*1024 + m)*DIN + k]
                               : whh[((size_t)dir*1024 + m)*256 + (k - DIN)];
        __syncthreads();
        #pragma unroll
        for (int mm = 0; mm < 16; ++mm) acc = fmaf(As[ty][mm], Bs[mm][tx], acc);
        __syncthreads();
    }
    outw[((size_t)dir*1024 + n)*KG + k] = f2bs(acc);
}

// ---------------- cooperative layer kernel: 32 groups x 8 members, 2 syncs/step ----------------
// r6-proven skeleton (single fused K-loop, block-local accumulators, full gsync x2).
// Adds: row-major comm via wave-local transpose publish (+tfence), zs||G3, phase4 diet.
template<int DIN, typename TIn, typename TOut>
__global__ __launch_bounds__(BLK)
void layer_coop(const TIn* __restrict__ in,        // (B,T,DIN)
                TOut* __restrict__ out,             // (B,T,512): dir writes [dir*256,+256)
                const short* __restrict__ Wg_,      // (2,768,KG) gate-only bf16
                const short* __restrict__ Wcb_,     // (2,1024,KG) Wcomb bf16
                const short* __restrict__ Wxp,      // (48,512)
                const short* __restrict__ Woutp,    // (256,512)
                const float* __restrict__ bsum_all, // (2,1024)
                const float* __restrict__ conv_w,   // (512,2)
                const float* __restrict__ conv_b,   // (512)
                const float* __restrict__ dtw,      // (512,16)
                const float* __restrict__ dtb,      // (512)
                const float* __restrict__ Dm,       // (512)
                const float* __restrict__ h_init, const float* __restrict__ c_init,
                float* __restrict__ h_fin, float* __restrict__ c_fin,
                u64* commAll, unsigned* cntAll, int layer)
{
    constexpr int KG = DIN + 256;
    constexpr int ASTR = DIN + 264;       // sA row stride (shorts)
    constexpr int NU = 16*DIN/BLK;        // u elems per thread
    const int tid = threadIdx.x;
    const int wv = tid >> 6, ln = tid & 63;
    const int lr = ln & 15, lq = ln >> 4;
    const int bid = blockIdx.x;
    const int xcd = bid & 7, slot = bid >> 3;
    const int g = xcd * 4 + (slot >> 3);           // group 0..31 (same-XCD packing heuristic)
    const int j = slot & 7;                        // member 0..7
    const int dir = g >> 4;
    const int b0 = (g & 15) * NBR;

    u64* cu = commAll + (size_t)g * GSTR;
    unsigned* cnt = cntAll + (layer * 32 + g) * 64;

    const short* Wg  = Wg_  + (size_t)dir * 768  * KG;
    const short* Wcb = Wcb_ + (size_t)dir * 1024 * KG;

    __shared__ __attribute__((aligned(16))) short sA[16*ASTR];   // [u | h]
    __shared__ __attribute__((aligned(16))) short sXm[16*520];   // full xm, y in-place
    __shared__ __attribute__((aligned(16))) short sZs[16*520];   // full silu(z)
    __shared__ __attribute__((aligned(16))) short sWxp[48*520];  // Wxp cached
    __shared__ __attribute__((aligned(16))) short sWo[32*520];   // Woutp own 32 rows cached
    __shared__ __attribute__((aligned(16))) short sT[8*256];     // per-wave 16x16 transpose tile
    __shared__ float sFs[16*36], sGs[16*36], sOs[16*36], sC[16*36];
    __shared__ float sXd[16*52];
    __shared__ float sBc[16];

    // ---- init ----
    for (int idx = tid; idx < 16*256; idx += BLK) {
        int r = idx >> 8, k = idx & 255;
        sA[r*ASTR + DIN + k] = f2bs(h_init[((size_t)dir*BB + b0 + r)*256 + k]);
    }
    for (int idx = tid; idx < 16*32; idx += BLK) {
        int r = idx >> 5, kk = idx & 31;
        sC[r*36 + kk] = c_init[((size_t)dir*BB + b0 + r)*256 + 32*j + kk];
    }
    for (int idx = tid; idx < 48*512; idx += BLK) {
        int r = idx >> 9, k = idx & 511;
        sWxp[r*520 + k] = Wxp[idx];
    }
    for (int idx = tid; idx < 32*512; idx += BLK) {
        int r = idx >> 9, k = idx & 511;
        sWo[r*520 + k] = Woutp[(size_t)(32*j + r)*512 + k];
    }
    // per-lane constants
    const int q1 = wv >> 1, sub = wv & 1;
    const int kk1 = 16*sub + lr;                   // local col in own 32-strip (G1, wv<6)
    const int n1 = 256*q1 + 32*j + kk1;            // gate-only Wcat' row
    const float bs1 = (wv < 6) ? bsum_all[dir*1024 + 256 + n1] : 0.f;
    const int ncl = 16*wv + lr;                    // fused-G2 local col 0..127
    const int c1 = 128*j + ncl;                    // xz channel
    float cw = 0.f, cb = 0.f;
    if (j < 4) { cw = conv_w[c1*2 + 1]; cb = conv_b[c1]; }
    const int nloc = wv*16 + lr;                   // G4 local col (valid wv<2)
    const int col4 = 32*j + nloc;
    const float bs4 = (wv < 2) ? bsum_all[dir*1024 + col4] : 0.f;
    float w16[16];
    #pragma unroll
    for (int p = 0; p < 16; ++p) w16[p] = dtw[tid*16 + p];
    const float dtbv = dtb[tid], Dmv = Dm[tid];

    // prefetch u(0) and stage it into sA now
    TIn utmp[NU];
    {
        const int tn = dir ? (TT-1) : 0;
        #pragma unroll
        for (int qq = 0; qq < NU; ++qq) {
            int idx = tid + qq*BLK;
            utmp[qq] = in[((size_t)(b0 + idx/DIN)*TT + tn)*DIN + (idx % DIN)];
        }
        #pragma unroll
        for (int qq = 0; qq < NU; ++qq) {
            int idx = tid + qq*BLK;
            sA[(idx/DIN)*ASTR + (idx % DIN)] = conv2bs(utmp[qq]);
        }
    }

    unsigned target = 8;

    for (int t = 0; t < TT; ++t) {
        const int t_in = dir ? (TT-1-t) : t;

        // ---- A: h from comm (t>0); contiguous b64 LDS writes (row-major comm) ----
        if (t > 0) {
            for (int idx = tid; idx < 1024; idx += BLK)
                *(u64*)&sA[(idx>>6)*ASTR + DIN + 4*(idx & 63)] = a_ldU(&cu[X_H + idx]);
        }
        __syncthreads();

        // ---- B: fused G1(f/g/o strips, wv<6) + G2'(xz via Wcomb, all waves), K=KG ----
        {
            f4 accG = (f4){0.f,0.f,0.f,0.f};
            f4 accC = (f4){0.f,0.f,0.f,0.f};
            const int arow = lr*ASTR + lq*8;
            const short* browG = &Wg[(size_t)(wv < 6 ? n1 : 0)*KG + lq*8];
            const short* browC = &Wcb[(size_t)c1*KG + lq*8];
            #pragma unroll 4
            for (int k0 = 0; k0 < KG; k0 += 32) {
                bf8 a = *(const bf8*)&sA[arow + k0];
                if (wv < 6) { bf8 b = *(const bf8*)&browG[k0]; accG = MFMA16(a, b, accG, 0, 0, 0); }
                bf8 b2 = *(const bf8*)&browC[k0]; accC = MFMA16(a, b2, accC, 0, 0, 0);
            }
            // epilogue: xz wave-local transpose -> row-major u64 publish
            short* tT = &sT[wv*256];
            #pragma unroll
            for (int jj = 0; jj < 4; ++jj) {
                float v = accC[jj];
                if (j < 4) v = fmaf(v, cw, cb);
                v = v * sigmoidf_(v);
                tT[(lq*4+jj)*16 + lr] = f2bs(v);
            }
            // gates into local LDS strips
            if (wv < 6) {
                #pragma unroll
                for (int jj = 0; jj < 4; ++jj) {
                    float v = accG[jj] + bs1;
                    int rr2 = lq*4 + jj;
                    if (q1 == 0)      sFs[rr2*36 + kk1] = sigmoidf_(v);
                    else if (q1 == 1) sGs[rr2*36 + kk1] = tanhf_(v);
                    else              sOs[rr2*36 + kk1] = sigmoidf_(v);
                }
            }
            tfence();   // order short-writes of tT before the u64 readback (r7-proven)
            const int rr = ln >> 2, cc = ln & 3;
            u64 val = *(const u64*)&tT[rr*16 + 4*cc];
            if (j < 4) a_stU(&cu[X_XM + rr*128 + 32*j     + 4*wv + cc], val);
            else       a_stU(&cu[X_ZS + rr*128 + 32*(j-4) + 4*wv + cc], val);
        }
        gsync(cnt, target); target += 8;   // S_a: xm/zs exchanged

        // ---- C: stage xm (contiguous b64) + issue u(t+1) prefetch ----
        for (int idx = tid; idx < 2048; idx += BLK)
            *(u64*)&sXm[(idx>>7)*520 + 4*(idx & 127)] = a_ldU(&cu[X_XM + idx]);
        if (t + 1 < TT) {
            const int tn = dir ? (TT-2-t) : (t+1);
            #pragma unroll
            for (int qq = 0; qq < NU; ++qq) {
                int idx = tid + qq*BLK;
                utmp[qq] = in[((size_t)(b0 + idx/DIN)*TT + tn)*DIN + (idx % DIN)];
            }
        }
        __syncthreads();

        // ---- D: G3 (waves 0-2) || zs staging (waves 3-7) ----
        if (wv < 3) {
            f4 acc = (f4){0.f,0.f,0.f,0.f};
            const int arow3 = lr*520 + lq*8;
            const short* brow = &sWxp[(wv*16 + lr)*520 + lq*8];
            #pragma unroll 4
            for (int k0 = 0; k0 < 512; k0 += 32) {
                bf8 a = *(const bf8*)&sXm[arow3 + k0];
                bf8 b = *(const bf8*)&brow[k0];
                acc = MFMA16(a, b, acc, 0, 0, 0);
            }
            #pragma unroll
            for (int jj = 0; jj < 4; ++jj)
                sXd[(lq*4+jj)*52 + wv*16 + lr] = acc[jj];
        } else {
            for (int idx = tid - 192; idx < 2048; idx += BLK - 192)
                *(u64*)&sZs[(idx>>7)*520 + 4*(idx & 127)] = a_ldU(&cu[X_ZS + idx]);
        }
        __syncthreads();

        // ---- E: bc once by 16 threads; then fused phase4 (dp inline, no live array) ----
        if (tid < 16) {
            float bc = 0.f;
            #pragma unroll
            for (int s = 0; s < 16; ++s) bc = fmaf(sXd[tid*52+16+s], sXd[tid*52+32+s], bc);
            sBc[tid] = bc;
        }
        __syncthreads();
        for (int r = 0; r < 16; ++r) {
            float dp = dtbv;
            #pragma unroll
            for (int p = 0; p < 16; ++p) dp = fmaf(sXd[r*52 + p], w16[p], dp);
            float xmv = bs2f(sXm[r*520 + tid]);
            float zsv = bs2f(sZs[r*520 + tid]);
            float yv = fmaf(softplusf_(dp), sBc[r], Dmv) * xmv * zsv;
            sXm[r*520 + tid] = f2bs(yv);       // y in-place (own column)
        }
        __syncthreads();

        // ---- stage u(t+1) into sA now (G4 window; off the post-sync path) ----
        if (t + 1 < TT) {
            #pragma unroll
            for (int qq = 0; qq < NU; ++qq) {
                int idx = tid + qq*BLK;
                sA[(idx/DIN)*ASTR + (idx % DIN)] = conv2bs(utmp[qq]);
            }
        }

        // ---- F: G4 (wv<2): own 32 cols; c/h update; transpose-publish h ----
        if (wv < 2) {
            f4 acc = (f4){0.f,0.f,0.f,0.f};
            const int arow4 = lr*520 + lq*8;
            const short* brow = &sWo[nloc*520 + lq*8];
            #pragma unroll 4
            for (int k0 = 0; k0 < 512; k0 += 32) {
                bf8 a = *(const bf8*)&sXm[arow4 + k0];
                bf8 b = *(const bf8*)&brow[k0];
                acc = MFMA16(a, b, acc, 0, 0, 0);
            }
            short* tT = &sT[wv*256];
            #pragma unroll
            for (int jj = 0; jj < 4; ++jj) {
                int r = lq*4 + jj;
                float i_t = sigmoidf_(acc[jj] + bs4);
                float cv = fmaf(sFs[r*36 + nloc], sC[r*36 + nloc], i_t * sGs[r*36 + nloc]);
                sC[r*36 + nloc] = cv;
                float hv = sOs[r*36 + nloc] * tanhf_(cv);
                tT[r*16 + lr] = f2bs(hv);
                storeval(&out[((size_t)(b0+r)*TT + t_in)*512 + (size_t)dir*256 + col4], hv);
            }
            tfence();   // order short-writes of tT before the u64 readback (r7-proven)
            const int rr = ln >> 2, cc = ln & 3;
            u64 val = *(const u64*)&tT[rr*16 + 4*cc];
            a_stU(&cu[X_H + rr*64 + 8*j + 4*wv + cc], val);
        }
        gsync(cnt, target); target += 8;   // S_b: h exchanged
    }

    // ---- finals: own 32-col slice (h from comm, c from LDS) ----
    for (int idx = tid; idx < 16*32; idx += BLK) {
        int r = idx >> 5, kk = idx & 31;
        int col = 32*j + kk;
        u64 v = a_ldU(&cu[X_H + r*64 + (col >> 2)]);
        size_t dst = ((size_t)dir*BB + b0 + r)*256 + col;
        h_fin[dst] = bs2f(sel4(v, col & 3));
        c_fin[dst] = sC[r*36 + kk];
    }
}

extern "C" void kernel_launch(void* const* d_in, const int* in_sizes, int n_in,
                              void* d_out, int out_size, void* d_ws, size_t ws_size,
                              hipStream_t stream)
{
    const float* x          = (const float*)d_in[0];
    const float* w_ih_l0    = (const float*)d_in[1];
    const float* w_hh_l0    = (const float*)d_in[2];
    const float* b_ih_l0    = (const float*)d_in[3];
    const float* b_hh_l0    = (const float*)d_in[4];
    const float* w_ih_l1    = (const float*)d_in[5];
    const float* w_hh_l1    = (const float*)d_in[6];
    const float* b_ih_l1    = (const float*)d_in[7];
    const float* b_hh_l1    = (const float*)d_in[8];
    const float* in_proj_w  = (const float*)d_in[9];
    const float* conv_w     = (const float*)d_in[10];
    const float* conv_b     = (const float*)d_in[11];
    const float* x_proj_w   = (const float*)d_in[12];
    const float* dt_proj_w  = (const float*)d_in[13];
    const float* dt_proj_b  = (const float*)d_in[14];
    const float* D_m        = (const float*)d_in[15];
    const float* out_proj_w = (const float*)d_in[16];

    short* wsu = (short*)d_ws;
    float* wsf = (float*)((char*)d_ws + FOFF);
    unsigned* cntAll = (unsigned*)(wsf + F_CNT);
    u64* commAll     = (u64*)(wsf + F_COMM);

    prep2<<<512, 256, 0, stream>>>(
        w_ih_l0, w_hh_l0, b_ih_l0, b_hh_l0,
        w_ih_l1, w_hh_l1, b_ih_l1, b_hh_l1,
        x_proj_w, out_proj_w, wsu, wsf);

    // Wcomb = in_proj_w @ Wcat_um (f32 accumulate, bf16 store)
    {
        dim3 g0(1024/16, 384/16, 2);
        wcomb_gemm<128><<<g0, 256, 0, stream>>>(in_proj_w, w_ih_l0, w_hh_l0, wsu + U_WCB0);
        dim3 g1(1024/16, 768/16, 2);
        wcomb_gemm<512><<<g1, 256, 0, stream>>>(in_proj_w, w_ih_l1, w_hh_l1, wsu + U_WCB1);
    }

    // layer 0: x fp32 (DIN=128) -> l0out bf16; finals -> H1/C1
    layer_coop<128, float, short><<<256, BLK, 0, stream>>>(
        x, wsu + U_L0,
        wsu + U_WC0, wsu + U_WCB0, wsu + U_XP, wsu + U_OUTP,
        wsf + F_BSUM0, conv_w, conv_b, dt_proj_w, dt_proj_b, D_m,
        wsf + F_H0, wsf + F_C0, wsf + F_H1, wsf + F_C1,
        commAll, cntAll, 0);

    // layer 1: l0out bf16 (DIN=512) -> d_out fp32; init from H1/C1
    layer_coop<512, short, float><<<256, BLK, 0, stream>>>(
        wsu + U_L0, (float*)d_out,
        wsu + U_WC1, wsu + U_WCB1, wsu + U_XP, wsu + U_OUTP,
        wsf + F_BSUM1, conv_w, conv_b, dt_proj_w, dt_proj_b, D_m,
        wsf + F_H1, wsf + F_C1, wsf + F_H0, wsf + F_C0,
        commAll, cntAll, 1);
}